// Round 4
// baseline (479.229 us; speedup 1.0000x reference)
//
#include <hip/hip_runtime.h>
#include <hip/hip_bf16.h>

// Problem constants
#define TDATA 100000
#define NE 500
#define NI 200
#define SUB 20
#define NB 3
#define TSYN 201

// Layout
#define SROW 100552              // 200 front pad + data + 352 tail pad
#define HROW 216                 // conv taps padded: k in [-8,207] at [k+8]
#define NSTEP_E 32               // K=500 -> 32 MFMA k-steps (zero-padded)
#define NSTEP_I 13               // K=200 -> 13 k-steps
#define NF4_E 4000               // 32*500/4 float4s per e-tile (64000 B)
#define NF4_I 1600               // 32*200/4 float4s per i-tile (25600 B)
#define NTILE 3125               // 100000/32 exactly, per matrix

// ws float offsets
#define OFF_HP  0                            // 2*20*216 = 8640 floats
#define OFF_BE  8640                         // e A-frags: 32*64*8 bf16 = 8192 float slots
#define OFF_BI  (OFF_BE + 8192)              // 16832; i A-frags: 14*64*8 bf16 = 3584 slots
#define OFF_INT (OFF_BI + 3584)              // 20416; inT = 40 rows x SROW

typedef __bf16 bf16x8 __attribute__((ext_vector_type(8)));
typedef float  f32x16 __attribute__((ext_vector_type(16)));

// ---------------------------------------------------------------------------
// Setup: conv taps | inT pad zeros | bf16 A-operand fragments (exact MFMA
// per-lane order: element j of lane l, k-step u -> C[s=l&31][k=16u+8*(l>>5)+j])
// Grid = 212*256 = 54272 exactly.  (unchanged — passed 4 rounds)
// ---------------------------------------------------------------------------
__global__ __launch_bounds__(256) void setup_kernel(
    const float* __restrict__ C_e, const float* __restrict__ C_i,
    const float* __restrict__ K_syn, const float* __restrict__ tau_syn,
    const float* __restrict__ delta_syn, float* __restrict__ ws)
{
    int idx = blockIdx.x * 256 + threadIdx.x;
    if (idx < 8640) {                        // ---- conv taps (zero-padded)
        int c = idx / (SUB * HROW);
        int rem = idx - c * (SUB * HROW);
        int s = rem / HROW;
        int k = (rem - s * HROW) - 8;
        float v = 0.f;
        if (k >= 0 && k < TSYN) {
            float ts = (float)k - delta_syn[s * 2 + c];
            ts = ts < 0.f ? 0.f : ts;
            #pragma unroll
            for (int b = 0; b < NB; b++) {
                float tt = ts / expf(tau_syn[b * 2 + c]);
                v += K_syn[(s * NB + b) * 2 + c] * tt * expf(-tt);
            }
        }
        ws[OFF_HP + idx] = v;
    } else if (idx < 30720) {                // ---- inT front/tail pad zeros
        int j = idx - 8640;
        const int PERROW = 552;              // 200 front + 352 tail
        int row = j / PERROW;
        int e = j - row * PERROW;
        int off = (e < 200) ? e : (200 + TDATA + (e - 200));
        ws[OFF_INT + (long)row * SROW + off] = 0.f;
    } else if (idx < 47104) {                // ---- e A-frags (bf16), 32 k-steps
        int j = idx - 30720;                 // 32*64*8 = 16384
        int step = j >> 9;
        int lane = (j >> 3) & 63;
        int jj = j & 7;
        int k = step * 16 + ((lane >> 5) << 3) + jj;
        int s = lane & 31;
        float v = (s < SUB && k < NE) ? C_e[s * NE + k] : 0.f;
        ((__hip_bfloat16*)(ws + OFF_BE))[j] = (__hip_bfloat16)v;
    } else {                                 // ---- i A-frags (bf16), 14 k-steps
        int j = idx - 47104;                 // 14*64*8 = 7168
        int step = j >> 9;
        int lane = (j >> 3) & 63;
        int jj = j & 7;
        int k = step * 16 + ((lane >> 5) << 3) + jj;
        int s = lane & 31;
        float v = (s < SUB && k < NI) ? C_i[s * NI + k] : 0.f;
        ((__hip_bfloat16*)(ws + OFF_BI))[j] = (__hip_bfloat16)v;
    }
}

// ---------------------------------------------------------------------------
// MFMA GEMM v6: REGISTER-staged streaming (LDS-DMA theory test).
//   v0/v2/v3 all pinned at ~5 GB/s/CU; common factor = either LDS-DMA
//   (global_load_lds: suspected low outstanding-miss cap per CU) or tiny
//   VGPR-limited MLP (v0).  v6 replicates the proven 6.3 TB/s copy pattern:
//   each thread issues 16 independent float4 loads (per wave-instr: 1 KB
//   contiguous; per block: one 64 KB contiguous region in flight), then
//   ds_write_b128 linearly -> LDS holds packed [32][K] row-major.
//   4 waves split K k-steps (u = w, w+4, ...), LDS cross-wave reduce (v2's,
//   proven), wave 0 stores.  K-tail k-steps read neighbor-row data x ZERO
//   A-frags (= 0, harmless); LDS tail region explicitly zeroed so row 31
//   never reads uninitialized LDS (NaN x 0 = NaN hazard).
//   All register arrays statically indexed (rule #20).
// ---------------------------------------------------------------------------
template<int K, int NSTEP, int NF4>
__device__ __forceinline__ void gemm6_body(
    const float* __restrict__ S, const float* __restrict__ wsA,
    float* __restrict__ inT, float* tile, int blk, int tid)
{
    constexpr int NJ = (NF4 + 255) / 256;    // e:16, i:7
    const int lane = tid & 63, wave = tid >> 6;

    // ---- phase 1: issue the whole tile as independent register loads ----
    const float4* src = (const float4*)(S + (long)blk * (32 * K));
    float4 v[NJ];
    #pragma unroll
    for (int j = 0; j < NJ; j++) {
        int idx = tid + 256 * j;
        if (idx < NF4) v[j] = src[idx];
    }

    // A-frags -> registers (L2-hot small region; covered by the same drain)
    const bf16x8* afr = (const bf16x8*)wsA;
    bf16x8 A[8];
    #pragma unroll
    for (int q = 0; q < 8; q++) {
        int u = wave + 4 * q;
        if (u < NSTEP) A[q] = afr[u * 64 + lane];
    }

    // ---- phase 2: register -> LDS (linear; LDS = packed [32][K] image) ----
    float4* t4 = (float4*)tile;
    #pragma unroll
    for (int j = 0; j < NJ; j++) {
        int idx = tid + 256 * j;
        if (idx < NF4) t4[idx] = v[j];
    }
    if (tid < 96)                            // zero the k-tail overrun region
        t4[NF4 + tid] = make_float4(0.f, 0.f, 0.f, 0.f);
    __syncthreads();

    // ---- phase 3: MFMA, wave w does k-steps u = w, w+4, ... ----
    const int n = lane & 31, h = lane >> 5;
    const float* r0 = tile + n * K;
    f32x16 acc = {};
    #pragma unroll
    for (int q = 0; q < 8; q++) {
        int u = wave + 4 * q;
        if (u < NSTEP) {
            const int kl = 16 * u + 8 * h;
            float4 lo = *(const float4*)(r0 + kl);
            float4 hi = *(const float4*)(r0 + kl + 4);
            bf16x8 b;
            b[0] = (__bf16)lo.x; b[1] = (__bf16)lo.y; b[2] = (__bf16)lo.z; b[3] = (__bf16)lo.w;
            b[4] = (__bf16)hi.x; b[5] = (__bf16)hi.y; b[6] = (__bf16)hi.z; b[7] = (__bf16)hi.w;
            acc = __builtin_amdgcn_mfma_f32_32x32x16_bf16(A[q], b, acc, 0, 0, 0);
        }
    }

    // ---- phase 4: cross-wave K-reduce through LDS (reuse tile; proven) ----
    __syncthreads();                          // all tile reads done
    if (wave != 0) {
        float4* dst = (float4*)(tile + ((wave - 1) * 64 + lane) * 16);
        dst[0] = make_float4(acc[0],  acc[1],  acc[2],  acc[3]);
        dst[1] = make_float4(acc[4],  acc[5],  acc[6],  acc[7]);
        dst[2] = make_float4(acc[8],  acc[9],  acc[10], acc[11]);
        dst[3] = make_float4(acc[12], acc[13], acc[14], acc[15]);
    }
    __syncthreads();
    if (wave == 0) {
        #pragma unroll
        for (int w = 0; w < 3; w++) {
            const float4* s4 = (const float4*)(tile + (w * 64 + lane) * 16);
            float4 p0 = s4[0], p1 = s4[1], p2 = s4[2], p3 = s4[3];
            acc[0]  += p0.x; acc[1]  += p0.y; acc[2]  += p0.z; acc[3]  += p0.w;
            acc[4]  += p1.x; acc[5]  += p1.y; acc[6]  += p1.z; acc[7]  += p1.w;
            acc[8]  += p2.x; acc[9]  += p2.y; acc[10] += p2.z; acc[11] += p2.w;
            acc[12] += p3.x; acc[13] += p3.y; acc[14] += p3.z; acc[15] += p3.w;
        }
        const long t = (long)blk * 32 + n;    // 32*3125 = 100000 exact
        #pragma unroll
        for (int r = 0; r < 16; r++) {
            int m = (r & 3) + 8 * (r >> 2) + 4 * h;
            if (m < SUB)
                inT[(long)m * SROW + 200 + t] = acc[r];
        }
    }
}

__global__ __launch_bounds__(256) void gemm_kernel(
    const float* __restrict__ Se, const float* __restrict__ Si,
    float* __restrict__ ws)
{
    __shared__ __align__(16) float tile[16384];   // 64 KB; covers max read 16011
    const int tid = threadIdx.x;
    if (!(blockIdx.x & 1))                   // e/i parity interleave (balance)
        gemm6_body<NE, NSTEP_E, NF4_E>(Se, ws + OFF_BE, ws + OFF_INT,
                                       tile, blockIdx.x >> 1, tid);
    else
        gemm6_body<NI, NSTEP_I, NF4_I>(Si, ws + OFF_BI,
                                       ws + OFF_INT + (long)SUB * SROW,
                                       tile, blockIdx.x >> 1, tid);
}

// ---------------------------------------------------------------------------
// Conv: round-0 version (benched clean; round-2 rewrite spilled to scratch).
// block = (s, 2048 t's); windows staged in LDS with i+(i>>5) swizzle;
// taps in LDS, broadcast ds_read_b128. Thread = 8 consecutive t's.
// ---------------------------------------------------------------------------
#define SW(i) ((i) + ((i) >> 5))

__global__ __launch_bounds__(256) void conv_kernel(
    const float* __restrict__ ws, float* __restrict__ out)
{
    __shared__ __align__(16) float W[2][2336];   // SW(2255)=2325 max
    __shared__ __align__(16) float HT[2][208];
    const int tid = threadIdx.x;
    const int s = blockIdx.y;
    const long t0 = (long)blockIdx.x * 2048;

    // stage windows: W[c][q] = row_c[t0 - 208 + q], q in [0,2256)
    for (int i = tid; i < 1128; i += 256) {
        int c = i >= 564;
        int i4 = i - c * 564;
        float4 v = *(const float4*)(ws + OFF_INT + (long)(c * SUB + s) * SROW
                                    + t0 - 8 + 4 * i4);
        int b = 4 * i4;
        int p = SW(b);                        // contiguous within aligned-4 runs
        W[c][p] = v.x; W[c][p + 1] = v.y; W[c][p + 2] = v.z; W[c][p + 3] = v.w;
    }
    if (tid < 104) {                          // taps: 2 channels x 208
        int c = tid >= 52;
        int j4 = (tid - c * 52) * 4;
        *(float4*)&HT[c][j4] =
            *(const float4*)(ws + OFF_HP + (c * SUB + s) * HROW + 8 + j4);
    }
    __syncthreads();

    float acc[8];
    #pragma unroll
    for (int r = 0; r < 8; r++) acc[r] = 0.f;

    #pragma unroll
    for (int c = 0; c < 2; c++) {
        #pragma unroll 2
        for (int g = 0; g < 26; g++) {
            int k0 = g << 3;
            int xb = (tid << 3) + 200 - k0;
            float x[16];
            #pragma unroll
            for (int q = 0; q < 16; q++) x[q] = W[c][SW(xb + q)];
            float h[8];
            *(float4*)&h[0] = *(const float4*)&HT[c][k0];
            *(float4*)&h[4] = *(const float4*)&HT[c][k0 + 4];
            #pragma unroll
            for (int j = 0; j < 8; j++)
                #pragma unroll
                for (int r = 0; r < 8; r++)
                    acc[r] += h[j] * x[8 + r - j];
        }
    }

    #pragma unroll
    for (int r = 0; r < 8; r++) {
        long t = t0 + 8 * tid + r;
        if (t < TDATA) out[t * SUB + s] = acc[r];
    }
}

// ---------------------------------------------------------------------------
extern "C" void kernel_launch(void* const* d_in, const int* in_sizes, int n_in,
                              void* d_out, int out_size, void* d_ws, size_t ws_size,
                              hipStream_t stream)
{
    const float* S_e     = (const float*)d_in[0];
    const float* S_i     = (const float*)d_in[1];
    const float* C_e     = (const float*)d_in[2];
    const float* C_i     = (const float*)d_in[3];
    const float* K_syn   = (const float*)d_in[4];
    const float* tau_syn = (const float*)d_in[5];
    const float* delta   = (const float*)d_in[6];
    float* out = (float*)d_out;
    float* ws  = (float*)d_ws;

    hipLaunchKernelGGL(setup_kernel, dim3(212), dim3(256), 0, stream,
                       C_e, C_i, K_syn, tau_syn, delta, ws);
    hipLaunchKernelGGL(gemm_kernel, dim3(2 * NTILE), dim3(256), 0, stream,
                       S_e, S_i, ws);
    hipLaunchKernelGGL(conv_kernel, dim3(49, SUB), dim3(256), 0, stream,
                       ws, out);
}

// Round 5
// 454.634 us; speedup vs baseline: 1.0541x; 1.0541x over previous
//
#include <hip/hip_runtime.h>
#include <hip/hip_bf16.h>

// Problem constants
#define TDATA 100000
#define NE 500
#define NI 200
#define SUB 20
#define NB 3
#define TSYN 201

// Layout
#define SROW 100552              // 200 front pad + data + 352 tail pad
#define HROW 216                 // conv taps padded: k in [-8,207] at [k+8]
#define NSTEP_E 32               // K=500 -> 32 MFMA k-steps (zero-padded)
#define NSTEP_I 13               // K=200 -> 13 k-steps
#define NF4_E 4000               // 32*500/4 float4s per e-tile (64000 B)
#define NF4_I 1600               // 32*200/4 float4s per i-tile (25600 B)
#define NTILE 3125               // 100000/32 exactly, per matrix

// ws float offsets
#define OFF_HP  0                            // 2*20*216 = 8640 floats
#define OFF_BE  8640                         // e A-frags: 32*64*8 bf16 = 8192 float slots
#define OFF_BI  (OFF_BE + 8192)              // 16832; i A-frags: 14*64*8 bf16 = 3584 slots
#define OFF_INT (OFF_BI + 3584)              // 20416; inT = 40 rows x SROW

typedef __bf16 bf16x8 __attribute__((ext_vector_type(8)));
typedef float  f32x16 __attribute__((ext_vector_type(16)));

// ---------------------------------------------------------------------------
// Setup: conv taps | inT pad zeros | bf16 A-operand fragments (exact MFMA
// per-lane order: element j of lane l, k-step u -> C[s=l&31][k=16u+8*(l>>5)+j])
// Grid = 212*256 = 54272 exactly.  (unchanged — passed 5 rounds)
// ---------------------------------------------------------------------------
__global__ __launch_bounds__(256) void setup_kernel(
    const float* __restrict__ C_e, const float* __restrict__ C_i,
    const float* __restrict__ K_syn, const float* __restrict__ tau_syn,
    const float* __restrict__ delta_syn, float* __restrict__ ws)
{
    int idx = blockIdx.x * 256 + threadIdx.x;
    if (idx < 8640) {                        // ---- conv taps (zero-padded)
        int c = idx / (SUB * HROW);
        int rem = idx - c * (SUB * HROW);
        int s = rem / HROW;
        int k = (rem - s * HROW) - 8;
        float v = 0.f;
        if (k >= 0 && k < TSYN) {
            float ts = (float)k - delta_syn[s * 2 + c];
            ts = ts < 0.f ? 0.f : ts;
            #pragma unroll
            for (int b = 0; b < NB; b++) {
                float tt = ts / expf(tau_syn[b * 2 + c]);
                v += K_syn[(s * NB + b) * 2 + c] * tt * expf(-tt);
            }
        }
        ws[OFF_HP + idx] = v;
    } else if (idx < 30720) {                // ---- inT front/tail pad zeros
        int j = idx - 8640;
        const int PERROW = 552;              // 200 front + 352 tail
        int row = j / PERROW;
        int e = j - row * PERROW;
        int off = (e < 200) ? e : (200 + TDATA + (e - 200));
        ws[OFF_INT + (long)row * SROW + off] = 0.f;
    } else if (idx < 47104) {                // ---- e A-frags (bf16), 32 k-steps
        int j = idx - 30720;                 // 32*64*8 = 16384
        int step = j >> 9;
        int lane = (j >> 3) & 63;
        int jj = j & 7;
        int k = step * 16 + ((lane >> 5) << 3) + jj;
        int s = lane & 31;
        float v = (s < SUB && k < NE) ? C_e[s * NE + k] : 0.f;
        ((__hip_bfloat16*)(ws + OFF_BE))[j] = (__hip_bfloat16)v;
    } else {                                 // ---- i A-frags (bf16), 14 k-steps
        int j = idx - 47104;                 // 14*64*8 = 7168
        int step = j >> 9;
        int lane = (j >> 3) & 63;
        int jj = j & 7;
        int k = step * 16 + ((lane >> 5) << 3) + jj;
        int s = lane & 31;
        float v = (s < SUB && k < NI) ? C_i[s * NI + k] : 0.f;
        ((__hip_bfloat16*)(ws + OFF_BI))[j] = (__hip_bfloat16)v;
    }
}

// ---------------------------------------------------------------------------
// MFMA GEMM v7: v6's register-staged streaming with the spill fixed.
//   Round-4 evidence: WRITE_SIZE 286MB (inT is 16MB) + FETCH +90MB = scratch
//   spill of the 16-deep float4 staging array; yet even spilling, the
//   contiguous wave-instruction pattern sustained 2.75 TB/s -> the pattern
//   is right, the register budget was not.
//   v7: 512-thread blocks. 64KB e-tile = 8 float4/thread held in flight
//   (32 VGPRs, not 64). Per CU: 2 blocks x 512 x 128B = 128KB outstanding
//   contiguous reads (~6x BW*latency product). 8 waves split the k-steps
//   (<=4 A-frags each), LDS cross-wave reduce (proven v2/v6), wave 0 stores.
//   K-tail: LDS tail zeroed (no uninit reads); mid-row overrun reads
//   neighbor-row finite data x ZERO A-frags. All static indexing (rule #20).
// ---------------------------------------------------------------------------
template<int K, int NSTEP, int NF4>
__device__ __forceinline__ void gemm7_body(
    const float* __restrict__ S, const float* __restrict__ wsA,
    float* __restrict__ inT, float* tile, int blk, int tid)
{
    constexpr int NJ  = (NF4 + 511) / 512;   // e:8, i:4  float4s per thread
    constexpr int NAQ = (NSTEP + 7) / 8;     // e:4, i:2  k-steps per wave
    const int lane = tid & 63, wave = tid >> 6;

    // ---- phase 1: whole tile as independent contiguous register loads ----
    const float4* src = (const float4*)(S + (long)blk * (32 * K));
    float4 v[NJ];
    #pragma unroll
    for (int j = 0; j < NJ; j++) {
        int idx = tid + 512 * j;
        if (idx < NF4) v[j] = src[idx];
    }

    // A-frags -> registers (L2-hot small region)
    const bf16x8* afr = (const bf16x8*)wsA;
    bf16x8 A[NAQ];
    #pragma unroll
    for (int q = 0; q < NAQ; q++) {
        int u = wave + 8 * q;
        if (u < NSTEP) A[q] = afr[u * 64 + lane];
    }

    // ---- phase 2: register -> LDS (linear; LDS = packed [32][K] image) ----
    float4* t4 = (float4*)tile;
    #pragma unroll
    for (int j = 0; j < NJ; j++) {
        int idx = tid + 512 * j;
        if (idx < NF4) t4[idx] = v[j];
    }
    if (tid < 96)                            // zero the k-tail overrun region
        t4[NF4 + tid] = make_float4(0.f, 0.f, 0.f, 0.f);
    __syncthreads();

    // ---- phase 3: MFMA, wave w does k-steps u = w, w+8, ... ----
    const int n = lane & 31, h = lane >> 5;
    const float* r0 = tile + n * K;
    f32x16 acc = {};
    #pragma unroll
    for (int q = 0; q < NAQ; q++) {
        int u = wave + 8 * q;
        if (u < NSTEP) {
            const int kl = 16 * u + 8 * h;
            float4 lo = *(const float4*)(r0 + kl);
            float4 hi = *(const float4*)(r0 + kl + 4);
            bf16x8 b;
            b[0] = (__bf16)lo.x; b[1] = (__bf16)lo.y; b[2] = (__bf16)lo.z; b[3] = (__bf16)lo.w;
            b[4] = (__bf16)hi.x; b[5] = (__bf16)hi.y; b[6] = (__bf16)hi.z; b[7] = (__bf16)hi.w;
            acc = __builtin_amdgcn_mfma_f32_32x32x16_bf16(A[q], b, acc, 0, 0, 0);
        }
    }

    // ---- phase 4: cross-wave K-reduce through LDS (reuse tile) ----
    __syncthreads();                          // all tile reads done
    if (wave != 0) {
        float4* dst = (float4*)(tile + ((wave - 1) * 64 + lane) * 16);
        dst[0] = make_float4(acc[0],  acc[1],  acc[2],  acc[3]);
        dst[1] = make_float4(acc[4],  acc[5],  acc[6],  acc[7]);
        dst[2] = make_float4(acc[8],  acc[9],  acc[10], acc[11]);
        dst[3] = make_float4(acc[12], acc[13], acc[14], acc[15]);
    }
    __syncthreads();
    if (wave == 0) {
        #pragma unroll
        for (int w = 0; w < 7; w++) {
            const float4* s4 = (const float4*)(tile + (w * 64 + lane) * 16);
            float4 p0 = s4[0], p1 = s4[1], p2 = s4[2], p3 = s4[3];
            acc[0]  += p0.x; acc[1]  += p0.y; acc[2]  += p0.z; acc[3]  += p0.w;
            acc[4]  += p1.x; acc[5]  += p1.y; acc[6]  += p1.z; acc[7]  += p1.w;
            acc[8]  += p2.x; acc[9]  += p2.y; acc[10] += p2.z; acc[11] += p2.w;
            acc[12] += p3.x; acc[13] += p3.y; acc[14] += p3.z; acc[15] += p3.w;
        }
        const long t = (long)blk * 32 + n;    // 32*3125 = 100000 exact
        #pragma unroll
        for (int r = 0; r < 16; r++) {
            int m = (r & 3) + 8 * (r >> 2) + 4 * h;
            if (m < SUB)
                inT[(long)m * SROW + 200 + t] = acc[r];
        }
    }
}

__global__ __launch_bounds__(512) void gemm_kernel(
    const float* __restrict__ Se, const float* __restrict__ Si,
    float* __restrict__ ws)
{
    __shared__ __align__(16) float tile[16384];   // 64 KB -> 2 blocks/CU
    const int tid = threadIdx.x;
    if (!(blockIdx.x & 1))                   // e/i parity interleave (balance)
        gemm7_body<NE, NSTEP_E, NF4_E>(Se, ws + OFF_BE, ws + OFF_INT,
                                       tile, blockIdx.x >> 1, tid);
    else
        gemm7_body<NI, NSTEP_I, NF4_I>(Si, ws + OFF_BI,
                                       ws + OFF_INT + (long)SUB * SROW,
                                       tile, blockIdx.x >> 1, tid);
}

// ---------------------------------------------------------------------------
// Conv: round-0 version (benched clean; the rolling-window rewrite spilled).
// block = (s, 2048 t's); windows staged in LDS with i+(i>>5) swizzle;
// taps in LDS, broadcast ds_read_b128. Thread = 8 consecutive t's.
// ---------------------------------------------------------------------------
#define SW(i) ((i) + ((i) >> 5))

__global__ __launch_bounds__(256) void conv_kernel(
    const float* __restrict__ ws, float* __restrict__ out)
{
    __shared__ __align__(16) float W[2][2336];   // SW(2255)=2325 max
    __shared__ __align__(16) float HT[2][208];
    const int tid = threadIdx.x;
    const int s = blockIdx.y;
    const long t0 = (long)blockIdx.x * 2048;

    // stage windows: W[c][q] = row_c[t0 - 208 + q], q in [0,2256)
    for (int i = tid; i < 1128; i += 256) {
        int c = i >= 564;
        int i4 = i - c * 564;
        float4 v = *(const float4*)(ws + OFF_INT + (long)(c * SUB + s) * SROW
                                    + t0 - 8 + 4 * i4);
        int b = 4 * i4;
        int p = SW(b);                        // contiguous within aligned-4 runs
        W[c][p] = v.x; W[c][p + 1] = v.y; W[c][p + 2] = v.z; W[c][p + 3] = v.w;
    }
    if (tid < 104) {                          // taps: 2 channels x 208
        int c = tid >= 52;
        int j4 = (tid - c * 52) * 4;
        *(float4*)&HT[c][j4] =
            *(const float4*)(ws + OFF_HP + (c * SUB + s) * HROW + 8 + j4);
    }
    __syncthreads();

    float acc[8];
    #pragma unroll
    for (int r = 0; r < 8; r++) acc[r] = 0.f;

    #pragma unroll
    for (int c = 0; c < 2; c++) {
        #pragma unroll 2
        for (int g = 0; g < 26; g++) {
            int k0 = g << 3;
            int xb = (tid << 3) + 200 - k0;
            float x[16];
            #pragma unroll
            for (int q = 0; q < 16; q++) x[q] = W[c][SW(xb + q)];
            float h[8];
            *(float4*)&h[0] = *(const float4*)&HT[c][k0];
            *(float4*)&h[4] = *(const float4*)&HT[c][k0 + 4];
            #pragma unroll
            for (int j = 0; j < 8; j++)
                #pragma unroll
                for (int r = 0; r < 8; r++)
                    acc[r] += h[j] * x[8 + r - j];
        }
    }

    #pragma unroll
    for (int r = 0; r < 8; r++) {
        long t = t0 + 8 * tid + r;
        if (t < TDATA) out[t * SUB + s] = acc[r];
    }
}

// ---------------------------------------------------------------------------
extern "C" void kernel_launch(void* const* d_in, const int* in_sizes, int n_in,
                              void* d_out, int out_size, void* d_ws, size_t ws_size,
                              hipStream_t stream)
{
    const float* S_e     = (const float*)d_in[0];
    const float* S_i     = (const float*)d_in[1];
    const float* C_e     = (const float*)d_in[2];
    const float* C_i     = (const float*)d_in[3];
    const float* K_syn   = (const float*)d_in[4];
    const float* tau_syn = (const float*)d_in[5];
    const float* delta   = (const float*)d_in[6];
    float* out = (float*)d_out;
    float* ws  = (float*)d_ws;

    hipLaunchKernelGGL(setup_kernel, dim3(212), dim3(256), 0, stream,
                       C_e, C_i, K_syn, tau_syn, delta, ws);
    hipLaunchKernelGGL(gemm_kernel, dim3(2 * NTILE), dim3(512), 0, stream,
                       S_e, S_i, ws);
    hipLaunchKernelGGL(conv_kernel, dim3(49, SUB), dim3(256), 0, stream,
                       ws, out);
}

// Round 6
// 388.101 us; speedup vs baseline: 1.2348x; 1.1714x over previous
//
#include <hip/hip_runtime.h>
#include <hip/hip_bf16.h>

// Problem constants
#define TDATA 100000
#define NE 500
#define NI 200
#define SUB 20
#define NB 3
#define TSYN 201

// Layout
#define SROW 100552              // 200 front pad + data + 352 tail pad
#define HROW 216                 // conv taps padded: k in [-8,207] at [k+8]
#define NSTEP_E 32               // K=500 -> 32 MFMA k-steps (zero-padded)
#define NSTEP_I 13               // K=200 -> 13 k-steps
#define NF4_E 4000               // 32*500/4 float4s per e-tile (64000 B)
#define NF4_I 1600               // 32*200/4 float4s per i-tile (25600 B)
#define NTILE 3125               // 100000/32 exactly, per matrix

// ws float offsets
#define OFF_HP  0                            // 2*20*216 = 8640 floats
#define OFF_BE  8640                         // e A-frags: 32*64*8 bf16 = 8192 float slots
#define OFF_BI  (OFF_BE + 8192)              // 16832; i A-frags: 14*64*8 bf16 = 3584 slots
#define OFF_INT (OFF_BI + 3584)              // 20416; inT = 40 rows x SROW

typedef __bf16 bf16x8 __attribute__((ext_vector_type(8)));
typedef float  f32x16 __attribute__((ext_vector_type(16)));

// ---------------------------------------------------------------------------
// Setup: conv taps | inT pad zeros | bf16 A-operand fragments (exact MFMA
// per-lane order: element j of lane l, k-step u -> C[s=l&31][k=16u+8*(l>>5)+j])
// Grid = 212*256 = 54272 exactly.  (unchanged — passed 6 rounds)
// ---------------------------------------------------------------------------
__global__ __launch_bounds__(256) void setup_kernel(
    const float* __restrict__ C_e, const float* __restrict__ C_i,
    const float* __restrict__ K_syn, const float* __restrict__ tau_syn,
    const float* __restrict__ delta_syn, float* __restrict__ ws)
{
    int idx = blockIdx.x * 256 + threadIdx.x;
    if (idx < 8640) {                        // ---- conv taps (zero-padded)
        int c = idx / (SUB * HROW);
        int rem = idx - c * (SUB * HROW);
        int s = rem / HROW;
        int k = (rem - s * HROW) - 8;
        float v = 0.f;
        if (k >= 0 && k < TSYN) {
            float ts = (float)k - delta_syn[s * 2 + c];
            ts = ts < 0.f ? 0.f : ts;
            #pragma unroll
            for (int b = 0; b < NB; b++) {
                float tt = ts / expf(tau_syn[b * 2 + c]);
                v += K_syn[(s * NB + b) * 2 + c] * tt * expf(-tt);
            }
        }
        ws[OFF_HP + idx] = v;
    } else if (idx < 30720) {                // ---- inT front/tail pad zeros
        int j = idx - 8640;
        const int PERROW = 552;              // 200 front + 352 tail
        int row = j / PERROW;
        int e = j - row * PERROW;
        int off = (e < 200) ? e : (200 + TDATA + (e - 200));
        ws[OFF_INT + (long)row * SROW + off] = 0.f;
    } else if (idx < 47104) {                // ---- e A-frags (bf16), 32 k-steps
        int j = idx - 30720;                 // 32*64*8 = 16384
        int step = j >> 9;
        int lane = (j >> 3) & 63;
        int jj = j & 7;
        int k = step * 16 + ((lane >> 5) << 3) + jj;
        int s = lane & 31;
        float v = (s < SUB && k < NE) ? C_e[s * NE + k] : 0.f;
        ((__hip_bfloat16*)(ws + OFF_BE))[j] = (__hip_bfloat16)v;
    } else {                                 // ---- i A-frags (bf16), 14 k-steps
        int j = idx - 47104;                 // 14*64*8 = 7168
        int step = j >> 9;
        int lane = (j >> 3) & 63;
        int jj = j & 7;
        int k = step * 16 + ((lane >> 5) << 3) + jj;
        int s = lane & 31;
        float v = (s < SUB && k < NI) ? C_i[s * NI + k] : 0.f;
        ((__hip_bfloat16*)(ws + OFF_BI))[j] = (__hip_bfloat16)v;
    }
}

// ---------------------------------------------------------------------------
// MFMA GEMM v8: v7 with the REAL spill fixed.
//   Evidence: v6 (256thr, 16-deep) and v7 (512thr, 8-deep) both show
//   WRITE_SIZE ~= 287 MB ~= TOTAL STAGED BYTES (280 MB) — invariant across
//   thread count / depth / VGPR count.  Per-thread spill can't do that:
//   the v[NJ] staging ARRAY lived in scratch wholesale (rule #20 — the
//   guarded unroll didn't resolve to static indices).  Even hauling 2x
//   bytes, the pattern sustained 2.94 TB/s -> load path is healthy.
//   v8: NAMED registers va..vh (manual unroll, if constexpr on depth);
//   loads clamped in-bounds (dup reads past NF4, harmless); only last
//   store guarded; A-frag loads AFTER the LDS writes (staging regs dead).
//   Rest identical to v7: 512 thr, 8 waves split k-steps, LDS cross-wave
//   reduce, wave 0 stores, zero-tail, e/i parity interleave.
// ---------------------------------------------------------------------------
template<int K, int NSTEP, int NF4>
__device__ __forceinline__ void gemm8_body(
    const float* __restrict__ S, const float* __restrict__ wsA,
    float* __restrict__ inT, float* tile, int blk, int tid)
{
    constexpr int NJ  = (NF4 + 511) / 512;   // e:8, i:4  float4s per thread
    constexpr int NAQ = (NSTEP + 7) / 8;     // e:4, i:2  k-steps per wave
    const int lane = tid & 63, wave = tid >> 6;

    // ---- phase 1: whole tile as named-register contiguous loads ----
    const float4* src = (const float4*)(S + (long)blk * (32 * K));
    float4* t4 = (float4*)tile;
#define IDX8(J)  (tid + 512 * (J))
#define CIDX8(J) (IDX8(J) < NF4 ? IDX8(J) : NF4 - 1)
    float4 va = src[CIDX8(0)];
    float4 vb = src[CIDX8(1)];
    float4 vc = src[CIDX8(2)];
    float4 vd = src[CIDX8(3)];
    float4 ve, vf, vg, vh;
    if constexpr (NJ == 8) {
        ve = src[CIDX8(4)];
        vf = src[CIDX8(5)];
        vg = src[CIDX8(6)];
        vh = src[CIDX8(7)];
    }

    // ---- phase 2: register -> LDS (linear; LDS = packed [32][K] image) ----
    t4[IDX8(0)] = va;
    t4[IDX8(1)] = vb;
    t4[IDX8(2)] = vc;
    if constexpr (NJ == 8) {
        t4[IDX8(3)] = vd;
        t4[IDX8(4)] = ve;
        t4[IDX8(5)] = vf;
        t4[IDX8(6)] = vg;
        if (IDX8(7) < NF4) t4[IDX8(7)] = vh;
    } else {
        if (IDX8(3) < NF4) t4[IDX8(3)] = vd;
    }
#undef IDX8
#undef CIDX8
    if (tid < 96)                            // zero the k-tail overrun region
        t4[NF4 + tid] = make_float4(0.f, 0.f, 0.f, 0.f);

    // A-frags -> registers (L2-hot small region; staging regs dead here)
    const bf16x8* afr = (const bf16x8*)wsA;
    bf16x8 A[NAQ];
    #pragma unroll
    for (int q = 0; q < NAQ; q++) {
        int u = wave + 8 * q;
        if (u < NSTEP) A[q] = afr[u * 64 + lane];
    }
    __syncthreads();

    // ---- phase 3: MFMA, wave w does k-steps u = w, w+8, ... ----
    const int n = lane & 31, h = lane >> 5;
    const float* r0 = tile + n * K;
    f32x16 acc = {};
    #pragma unroll
    for (int q = 0; q < NAQ; q++) {
        int u = wave + 8 * q;
        if (u < NSTEP) {
            const int kl = 16 * u + 8 * h;
            float4 lo = *(const float4*)(r0 + kl);
            float4 hi = *(const float4*)(r0 + kl + 4);
            bf16x8 b;
            b[0] = (__bf16)lo.x; b[1] = (__bf16)lo.y; b[2] = (__bf16)lo.z; b[3] = (__bf16)lo.w;
            b[4] = (__bf16)hi.x; b[5] = (__bf16)hi.y; b[6] = (__bf16)hi.z; b[7] = (__bf16)hi.w;
            acc = __builtin_amdgcn_mfma_f32_32x32x16_bf16(A[q], b, acc, 0, 0, 0);
        }
    }

    // ---- phase 4: cross-wave K-reduce through LDS (reuse tile) ----
    __syncthreads();                          // all tile reads done
    if (wave != 0) {
        float4* dst = (float4*)(tile + ((wave - 1) * 64 + lane) * 16);
        dst[0] = make_float4(acc[0],  acc[1],  acc[2],  acc[3]);
        dst[1] = make_float4(acc[4],  acc[5],  acc[6],  acc[7]);
        dst[2] = make_float4(acc[8],  acc[9],  acc[10], acc[11]);
        dst[3] = make_float4(acc[12], acc[13], acc[14], acc[15]);
    }
    __syncthreads();
    if (wave == 0) {
        #pragma unroll
        for (int w = 0; w < 7; w++) {
            const float4* s4 = (const float4*)(tile + (w * 64 + lane) * 16);
            float4 p0 = s4[0], p1 = s4[1], p2 = s4[2], p3 = s4[3];
            acc[0]  += p0.x; acc[1]  += p0.y; acc[2]  += p0.z; acc[3]  += p0.w;
            acc[4]  += p1.x; acc[5]  += p1.y; acc[6]  += p1.z; acc[7]  += p1.w;
            acc[8]  += p2.x; acc[9]  += p2.y; acc[10] += p2.z; acc[11] += p2.w;
            acc[12] += p3.x; acc[13] += p3.y; acc[14] += p3.z; acc[15] += p3.w;
        }
        const long t = (long)blk * 32 + n;    // 32*3125 = 100000 exact
        #pragma unroll
        for (int r = 0; r < 16; r++) {
            int m = (r & 3) + 8 * (r >> 2) + 4 * h;
            if (m < SUB)
                inT[(long)m * SROW + 200 + t] = acc[r];
        }
    }
}

__global__ __launch_bounds__(512) void gemm_kernel(
    const float* __restrict__ Se, const float* __restrict__ Si,
    float* __restrict__ ws)
{
    __shared__ __align__(16) float tile[16384];   // 64 KB -> 2 blocks/CU
    const int tid = threadIdx.x;
    if (!(blockIdx.x & 1))                   // e/i parity interleave (balance)
        gemm8_body<NE, NSTEP_E, NF4_E>(Se, ws + OFF_BE, ws + OFF_INT,
                                       tile, blockIdx.x >> 1, tid);
    else
        gemm8_body<NI, NSTEP_I, NF4_I>(Si, ws + OFF_BI,
                                       ws + OFF_INT + (long)SUB * SROW,
                                       tile, blockIdx.x >> 1, tid);
}

// ---------------------------------------------------------------------------
// Conv: round-0 version (benched clean; the rolling-window rewrite spilled).
// block = (s, 2048 t's); windows staged in LDS with i+(i>>5) swizzle;
// taps in LDS, broadcast ds_read_b128. Thread = 8 consecutive t's.
// ---------------------------------------------------------------------------
#define SW(i) ((i) + ((i) >> 5))

__global__ __launch_bounds__(256) void conv_kernel(
    const float* __restrict__ ws, float* __restrict__ out)
{
    __shared__ __align__(16) float W[2][2336];   // SW(2255)=2325 max
    __shared__ __align__(16) float HT[2][208];
    const int tid = threadIdx.x;
    const int s = blockIdx.y;
    const long t0 = (long)blockIdx.x * 2048;

    // stage windows: W[c][q] = row_c[t0 - 208 + q], q in [0,2256)
    for (int i = tid; i < 1128; i += 256) {
        int c = i >= 564;
        int i4 = i - c * 564;
        float4 v = *(const float4*)(ws + OFF_INT + (long)(c * SUB + s) * SROW
                                    + t0 - 8 + 4 * i4);
        int b = 4 * i4;
        int p = SW(b);                        // contiguous within aligned-4 runs
        W[c][p] = v.x; W[c][p + 1] = v.y; W[c][p + 2] = v.z; W[c][p + 3] = v.w;
    }
    if (tid < 104) {                          // taps: 2 channels x 208
        int c = tid >= 52;
        int j4 = (tid - c * 52) * 4;
        *(float4*)&HT[c][j4] =
            *(const float4*)(ws + OFF_HP + (c * SUB + s) * HROW + 8 + j4);
    }
    __syncthreads();

    float acc[8];
    #pragma unroll
    for (int r = 0; r < 8; r++) acc[r] = 0.f;

    #pragma unroll
    for (int c = 0; c < 2; c++) {
        #pragma unroll 2
        for (int g = 0; g < 26; g++) {
            int k0 = g << 3;
            int xb = (tid << 3) + 200 - k0;
            float x[16];
            #pragma unroll
            for (int q = 0; q < 16; q++) x[q] = W[c][SW(xb + q)];
            float h[8];
            *(float4*)&h[0] = *(const float4*)&HT[c][k0];
            *(float4*)&h[4] = *(const float4*)&HT[c][k0 + 4];
            #pragma unroll
            for (int j = 0; j < 8; j++)
                #pragma unroll
                for (int r = 0; r < 8; r++)
                    acc[r] += h[j] * x[8 + r - j];
        }
    }

    #pragma unroll
    for (int r = 0; r < 8; r++) {
        long t = t0 + 8 * tid + r;
        if (t < TDATA) out[t * SUB + s] = acc[r];
    }
}

// ---------------------------------------------------------------------------
extern "C" void kernel_launch(void* const* d_in, const int* in_sizes, int n_in,
                              void* d_out, int out_size, void* d_ws, size_t ws_size,
                              hipStream_t stream)
{
    const float* S_e     = (const float*)d_in[0];
    const float* S_i     = (const float*)d_in[1];
    const float* C_e     = (const float*)d_in[2];
    const float* C_i     = (const float*)d_in[3];
    const float* K_syn   = (const float*)d_in[4];
    const float* tau_syn = (const float*)d_in[5];
    const float* delta   = (const float*)d_in[6];
    float* out = (float*)d_out;
    float* ws  = (float*)d_ws;

    hipLaunchKernelGGL(setup_kernel, dim3(212), dim3(256), 0, stream,
                       C_e, C_i, K_syn, tau_syn, delta, ws);
    hipLaunchKernelGGL(gemm_kernel, dim3(2 * NTILE), dim3(512), 0, stream,
                       S_e, S_i, ws);
    hipLaunchKernelGGL(conv_kernel, dim3(49, SUB), dim3(256), 0, stream,
                       ws, out);
}